// Round 5
// baseline (183.189 us; speedup 1.0000x reference)
//
#include <hip/hip_runtime.h>
#include <stdint.h>
#include <math.h>

#define C_NUM 2048
#define N_TOT 4096
#define B_TOT 4096
#define KNOWN 1024

typedef __attribute__((ext_vector_type(8))) short short8;
typedef __attribute__((ext_vector_type(4))) float f32x4;

__device__ __forceinline__ unsigned short f2bf(float x) {
  unsigned u = __float_as_uint(x);
  unsigned r = (u + 0x7fffu + ((u >> 16) & 1u)) >> 16;
  return (unsigned short)r;
}

__device__ __forceinline__ void gld16(const void* g, void* l) {
  __builtin_amdgcn_global_load_lds(
      (const __attribute__((address_space(1))) void*)g,
      (__attribute__((address_space(3))) void*)l, 16, 0, 0);
}

// ---- Kernel 1: transpose + bf16 convert + colsum/norm2 partials ----------
__global__ void transpose_stats_kernel(const float* __restrict__ prob,
                                       const float* __restrict__ prob_s,
                                       float* __restrict__ colsum,
                                       float* __restrict__ norm2,
                                       unsigned short* __restrict__ Pn) {
  __shared__ float tile[64][65];
  int tx = threadIdx.x;          // 0..63
  int ty = threadIdx.y;          // 0..3
  int c0 = blockIdx.x * 64;      // class tile (0..4095)
  int b0 = blockIdx.y * 64;      // batch tile
  const float* src = (c0 < C_NUM) ? prob : prob_s;
  int colbase = (c0 & (C_NUM - 1)) + tx;
  float s = 0.f, s2 = 0.f;
#pragma unroll
  for (int r = 0; r < 16; ++r) {
    int b = b0 + r * 4 + ty;
    float v = src[(size_t)b * C_NUM + colbase];
    tile[r * 4 + ty][tx] = v;
    s += v;
    s2 += v * v;
  }
  atomicAdd(&colsum[c0 + tx], s);
  atomicAdd(&norm2[c0 + tx], s2);
  __syncthreads();
#pragma unroll
  for (int r = 0; r < 16; ++r) {
    int i = c0 + r * 4 + ty;
    Pn[(size_t)i * B_TOT + b0 + tx] = f2bf(tile[tx][r * 4 + ty]);
  }
}

// ---- Kernel 2: invn[i] = 1/max(||P_i||, eps) ------------------------------
__global__ void invnorm_kernel(const float* __restrict__ norm2,
                               float* __restrict__ invn) {
  int i = blockIdx.x * 256 + threadIdx.x;
  invn[i] = 1.0f / fmaxf(sqrtf(norm2[i]), 1e-8f);
}

// ---- Kernel 3: symmetric fused GEMM + softmax-denominator epilogue -------
// Tile 64(M)x128(N), 256 threads = 4 waves (2x2), per-wave 32x64 (acc[2][4]).
// Triangular-ish grid over (64 row-panels x 32 col-panels): block (it,jt)
// included iff jt >= it>>1 -> 1056 jobs (every {i<j} pair in exactly one
// block; epilogue contributes only j>i entries, to BOTH rows i and j).
// 2-phase double-buffered LDS (24 KB), granule swizzle (phys=(klog+row>>1)&3)
// on both the pre-permuted global source and the ds_read address.
__global__ __launch_bounds__(256) void simgemm_kernel(
    const unsigned short* __restrict__ Pn,
    const float* __restrict__ invn,
    float* __restrict__ sumexp,
    float* __restrict__ pos) {
  __shared__ __align__(16) char lds[24576];  // buf b: A at b*12288, B at +4096

  const int tid = threadIdx.x;
  const int l = tid & 63;
  const int w = tid >> 6;            // wave 0..3
  const int wr = w >> 1, wc = w & 1; // 2x2 wave grid

  // decode job -> (it, jt): for it, jt runs it>>1 .. 31
  int t = blockIdx.x;
  int it = 0, cnt = 32;
  while (t >= cnt) { t -= cnt; ++it; cnt = 32 - (it >> 1); }
  const int jt = (it >> 1) + t;
  const int ib = it * 64;    // 64 rows
  const int jb = jt * 128;   // 128 cols

  // staging: thread tid fills LDS linear offset tid*16 (row=tid>>2, physg=tid&3)
  // logical granule = (physg - (row>>1)) & 3  (same for all q since q*64 rows)
  const int srow = tid >> 2;
  const int glog = ((tid & 3) - (tid >> 3)) & 3;
  const char* gA  = (const char*)Pn + (size_t)(ib + srow) * (B_TOT * 2) + glog * 16;
  const char* gB0 = (const char*)Pn + (size_t)(jb + srow) * (B_TOT * 2) + glog * 16;
  const char* gB1 = gB0 + (size_t)64 * (B_TOT * 2);
  const int ldsOf = tid * 16;

  f32x4 acc[2][4];
#pragma unroll
  for (int a = 0; a < 2; ++a)
#pragma unroll
    for (int b = 0; b < 4; ++b)
      acc[a][b] = (f32x4){0.f, 0.f, 0.f, 0.f};

  // fragment read geometry: rows of 64B (BK=32), 4 granules of 16B, swizzled
  const int arow = wr * 32 + (l & 15);
  const int brow = wc * 64 + (l & 15);
  const int klog = l >> 4;
  const int agran = (klog + (arow >> 1)) & 3;  // fm*16 rows shift slot by 8 == 0 mod 4
  const int bgran = (klog + (brow >> 1)) & 3;

#define STAGE(buf, koff)                                        \
  do {                                                          \
    gld16(gA  + (koff), lds + (buf) * 12288 + ldsOf);           \
    gld16(gB0 + (koff), lds + (buf) * 12288 + 4096 + ldsOf);    \
    gld16(gB1 + (koff), lds + (buf) * 12288 + 8192 + ldsOf);    \
  } while (0)

  STAGE(0, 0);
  __syncthreads();

  int cur = 0;
  const int NT = B_TOT / 32;   // 128 K-tiles
  for (int kt = 0; kt < NT; ++kt) {
    if (kt + 1 < NT) STAGE(cur ^ 1, (size_t)(kt + 1) * 64);

    const char* Abase = lds + cur * 12288;
    const char* Bbase = Abase + 4096;

    short8 af[2], bf[4];
#pragma unroll
    for (int f = 0; f < 2; ++f)
      af[f] = *(const short8*)(Abase + (arow + f * 16) * 64 + agran * 16);
#pragma unroll
    for (int f = 0; f < 4; ++f)
      bf[f] = *(const short8*)(Bbase + (brow + f * 16) * 64 + bgran * 16);

#pragma unroll
    for (int fm = 0; fm < 2; ++fm)
#pragma unroll
      for (int fn = 0; fn < 4; ++fn)
        acc[fm][fn] = __builtin_amdgcn_mfma_f32_16x16x32_bf16(
            af[fm], bf[fn], acc[fm][fn], 0, 0, 0);

    __syncthreads();
    cur ^= 1;
  }
#undef STAGE

  // epilogue: v = 2*dot*invn[i]*invn[j]; contribute ONLY j>i entries, to both
  // rows. pos pair written when j == i^2048 (i<2048 side).
  float invj[4];
#pragma unroll
  for (int fn = 0; fn < 4; ++fn)
    invj[fn] = invn[jb + wc * 64 + fn * 16 + (l & 15)];

  float cs[4] = {0.f, 0.f, 0.f, 0.f};
#pragma unroll
  for (int fm = 0; fm < 2; ++fm) {
#pragma unroll
    for (int r = 0; r < 4; ++r) {
      const int i = ib + wr * 32 + fm * 16 + (l >> 4) * 4 + r;
      const float invi = invn[i];
      float rs = 0.f;
#pragma unroll
      for (int fn = 0; fn < 4; ++fn) {
        const int j = jb + wc * 64 + fn * 16 + (l & 15);
        float v = acc[fm][fn][r] * 2.0f * invi * invj[fn];
        if (j > i) {
          if (j == (i ^ 2048)) {
            pos[i] = v;
            pos[j] = v;
          } else {
            float e = __expf(v);
            rs += (((i & 1024) == 0) && (j < KNOWN)) ? 1.0f : e;
            cs[fn] += (((j & 1024) == 0) && (i < KNOWN)) ? 1.0f : e;
          }
        }
      }
      rs += __shfl_xor(rs, 1);
      rs += __shfl_xor(rs, 2);
      rs += __shfl_xor(rs, 4);
      rs += __shfl_xor(rs, 8);
      if ((l & 15) == 0 && rs != 0.f) atomicAdd(&sumexp[i], rs);
    }
  }
#pragma unroll
  for (int fn = 0; fn < 4; ++fn) {
    cs[fn] += __shfl_xor(cs[fn], 16);
    cs[fn] += __shfl_xor(cs[fn], 32);
  }
  if (l < 16) {
#pragma unroll
    for (int fn = 0; fn < 4; ++fn)
      if (cs[fn] != 0.f)
        atomicAdd(&sumexp[jb + wc * 64 + fn * 16 + l], cs[fn]);
  }
}

// ---- Kernel 4: finalize ---------------------------------------------------
__device__ float block_reduce_256(float v, volatile float* red) {
#pragma unroll
  for (int m = 32; m >= 1; m >>= 1) v += __shfl_xor(v, m);
  __syncthreads();
  if ((threadIdx.x & 63) == 0) red[threadIdx.x >> 6] = v;
  __syncthreads();
  return red[0] + red[1] + red[2] + red[3];
}

__global__ void finalize_kernel(const float* __restrict__ colsum,
                                const float* __restrict__ sumexp,
                                const float* __restrict__ pos,
                                float* __restrict__ out) {
  __shared__ float red[4];
  int t = threadIdx.x;
  float ce = 0.f, t1 = 0.f, t2 = 0.f;
  for (int i = t; i < N_TOT; i += 256) ce += logf(sumexp[i]) - pos[i];
  for (int c = t; c < C_NUM; c += 256) t1 += colsum[c];
  for (int c = t; c < C_NUM; c += 256) t2 += colsum[C_NUM + c];
  ce = block_reduce_256(ce, red);
  t1 = block_reduce_256(t1, red);
  t2 = block_reduce_256(t2, red);
  float e1 = 0.f, e2 = 0.f;
  for (int c = t; c < C_NUM; c += 256) {
    float m = colsum[c] / t1;
    e1 += m * logf(m);
  }
  for (int c = t; c < C_NUM; c += 256) {
    float m = colsum[C_NUM + c] / t2;
    e2 += m * logf(m);
  }
  e1 = block_reduce_256(e1, red);
  e2 = block_reduce_256(e2, red);
  if (t == 0) {
    float reg = logf((float)C_NUM) + e1 + logf((float)C_NUM) + e2;
    out[0] = ce / (float)N_TOT + reg;
  }
}

extern "C" void kernel_launch(void* const* d_in, const int* in_sizes, int n_in,
                              void* d_out, int out_size, void* d_ws, size_t ws_size,
                              hipStream_t stream) {
  const float* prob = (const float*)d_in[0];
  const float* prob_s = (const float*)d_in[1];
  float* out = (float*)d_out;

  char* ws = (char*)d_ws;
  unsigned short* Pn = (unsigned short*)ws;                     // 32 MB bf16
  float* norm2 = (float*)(ws + (size_t)N_TOT * B_TOT * 2);      // 4096 f32
  float* colsum = norm2 + N_TOT;                                // 4096 f32
  float* sumexp = colsum + N_TOT;                               // 4096 f32
  float* invn = sumexp + N_TOT;                                 // 4096 f32
  float* pos = invn + N_TOT;                                    // 4096 f32

  // zero the atomic accumulators (norm2, colsum, sumexp contiguous)
  hipMemsetAsync(norm2, 0, (size_t)3 * N_TOT * sizeof(float), stream);

  transpose_stats_kernel<<<dim3(64, 64), dim3(64, 4), 0, stream>>>(
      prob, prob_s, colsum, norm2, Pn);
  invnorm_kernel<<<16, 256, 0, stream>>>(norm2, invn);
  simgemm_kernel<<<1056, 256, 0, stream>>>(Pn, invn, sumexp, pos);
  finalize_kernel<<<1, 256, 0, stream>>>(colsum, sumexp, pos, out);
}